// Round 8
// baseline (72.268 us; speedup 1.0000x reference)
//
#include <hip/hip_runtime.h>
#include <math.h>

#define HH 512
#define WW 512

__device__ __constant__ float YTAB[64] = {
    16,11,10,16,24,40,51,61,
    12,12,14,19,26,58,60,55,
    14,13,16,24,40,57,69,56,
    14,17,22,29,51,87,80,62,
    18,22,37,56,68,109,103,77,
    24,35,55,64,81,104,113,92,
    49,64,78,87,103,121,120,101,
    72,92,95,98,112,100,103,99};
__device__ __constant__ float CTAB[64] = {
    17,18,24,47,99,99,99,99,
    18,21,26,66,99,99,99,99,
    24,26,56,99,99,99,99,99,
    47,66,99,99,99,99,99,99,
    99,99,99,99,99,99,99,99,
    99,99,99,99,99,99,99,99,
    99,99,99,99,99,99,99,99,
    99,99,99,99,99,99,99,99};

// fp32 DCT basis exactly as numpy: cos(fp64 arg) cast to float32.
__device__ float g_Af[64];

__global__ void init_basis()
{
    int i = threadIdx.x;            // 0..63
    int x = i >> 3, u = i & 7;
    double arg = (double)((2 * x + 1) * u) * 3.14159265358979323846 / 16.0;
    g_Af[i] = (float)cos(arg);
}

// One workgroup = one 16x16 tile. 6 waves: 0-3 -> four Y blocks, 4 -> Cb,
// 5 -> Cr. Pre-round arithmetic replicates the np reference bit-for-bit:
//  - color: elementwise/noblas-matmul left-assoc mul/add, NO fma
//    (fingerprint-verified: flip A vanishes R4->R5)
//  - chroma mean: paired (p00+p01)+(p10+p11), /4 (np multi-axis reduce,
//    inner contiguous len-2 axis first)
//  - DCT einsum: jnp.einsum semantics preserved -> optimize='optimal' ->
//    two tensordot/sgemm contractions (path (0,1): contract x, then y).
//    OpenBLAS sgemm accumulates each output as a single ascending-k FMA
//    chain from 0, fp32 intermediate T1:
//      T1[y,u]  = fmaf(X[7,y],A[7,u], ... fmaf(X[0,y],A[0,u], 0))
//      raw[u,v] = fmaf(T1[7,u],A[7,v], ... fmaf(T1[0,u],A[0,v], 0))
// Post-round (IDCT onward) only needs ~1e-3: factored, fmaf allowed.
__global__ __launch_bounds__(384) void jpeg_fused(const float* __restrict__ in,
                                                  float* __restrict__ out)
{
#pragma clang fp contract(off)
    __shared__ float Yt[16][17];               // y-128 staged; reused for y2
    __shared__ float CBt[16][17];              // cb (+128 form)
    __shared__ float CRt[16][17];              // cr (+128 form)
    __shared__ float Ab[64];                   // basis A[x][u], fp32
    __shared__ float bufX[6][64];              // X block (pixel-domain, -128)
    __shared__ float bufG[6][64];              // deq*alpha2 (freq domain)
    __shared__ __align__(16) float bufI[6][64]; // T1 (pass1), later IDCT temp
    __shared__ float Cout[2][64];              // cb2, cr2 results

    const int tid  = threadIdx.x;
    const int wid  = tid >> 6;
    const int lane = tid & 63;
    const int r    = lane >> 3;
    const int c    = lane & 7;

    const int t  = blockIdx.x;
    const int b  = t >> 10;          // 1024 tiles per image (32x32)
    const int th = (t >> 5) & 31;
    const int tw = t & 31;
    const int h0 = th * 16;
    const int w0 = tw * 16;

    // ---- P0: basis + stage YCbCr (numpy fp32 noblas semantics, NO fma)
    if (tid < 64) Ab[tid] = g_Af[tid];
    if (tid < 256) {
        int pr = tid >> 4, pc = tid & 15;
        size_t base = ((size_t)b * 3 * HH + (size_t)(h0 + pr)) * WW + (w0 + pc);
        float rv = in[base];
        float gv = in[base + (size_t)HH * WW];
        float bv = in[base + 2 * (size_t)HH * WW];
        rv = fminf(fmaxf(rv, 0.f), 1.f) * 255.f;     // clip, then one rn mul
        gv = fminf(fmaxf(gv, 0.f), 1.f) * 255.f;
        bv = fminf(fmaxf(bv, 0.f), 1.f) * 255.f;
        // noblas matmul: acc=0; k ascending: acc = rn(acc + rn(a*b)) — left-assoc
        float y  = ((rv * 0.299f)     + (gv * 0.587f))     + (bv * 0.114f);
        float cb = ((rv * -0.168736f) + (gv * -0.331264f)) + (bv * 0.5f);
        float cr = ((rv * 0.5f)       + (gv * -0.418688f)) + (bv * -0.081312f);
        cb = cb + 128.f;                              // +SHIFT1, separate rn add
        cr = cr + 128.f;
        Yt[pr][pc]  = y - 128.f;                      // (y+0) then blocks-128
        CBt[pr][pc] = cb;
        CRt[pr][pc] = cr;
    }
    __syncthreads();

    // per-lane basis columns: Au[k]=A[k][r], Av[k]=A[k][c]
    float Au[8], Av[8];
#pragma unroll
    for (int k = 0; k < 8; ++k) { Au[k] = Ab[k * 8 + r]; Av[k] = Ab[k * 8 + c]; }
    const float qt = (wid < 4) ? YTAB[lane] : CTAB[lane];   // *1.0 at quality 50

    // ---- P1: X (pixel block minus 128) -> bufX[wid][r*8+c]  (per-wave private)
    {
        float xv;
        if (wid < 4) {
            int qy = wid >> 1, qx = wid & 1;
            xv = Yt[qy * 8 + r][qx * 8 + c];
        } else {
            const float (*Cs)[17] = (wid == 4) ? CBt : CRt;
            float p00 = Cs[2 * r][2 * c],     p01 = Cs[2 * r][2 * c + 1];
            float p10 = Cs[2 * r + 1][2 * c], p11 = Cs[2 * r + 1][2 * c + 1];
            float s01 = p00 + p01;                   // inner contiguous pair
            float s23 = p10 + p11;
            float m   = (s01 + s23) / 4.0f;          // paired, then true-div
            xv = m - 128.f;
        }
        bufX[wid][lane] = xv;
    }
    // wave-private LDS, lockstep lanes: no block barrier needed between phases

    // ---- P2a: sgemm pass 1 (contract x): T1[y,u], lane (y=r, u=c).
    //           Single FMA chain from 0, ascending x.
    {
        float acc = 0.f;
#pragma unroll
        for (int x = 0; x < 8; ++x)
            acc = fmaf(bufX[wid][x * 8 + r], Av[x], acc);  // Av[x]=A[x][c]=A[x][u]
        bufI[wid][r * 8 + c] = acc;                        // T1[y*8+u], fp32
    }

    // ---- P2b: sgemm pass 2 (contract y): raw[u,v], lane (u=r, v=c).
    //           Single FMA chain from 0, ascending y.
    float acc2 = 0.f;
#pragma unroll
    for (int y = 0; y < 8; ++y)
        acc2 = fmaf(bufI[wid][y * 8 + r], Av[y], acc2);    // Av[y]=A[y][c]=A[y][v]

    // ---- P3: scale, quantize (bit-critical through rintf), dequant
    {
        float auf = (r == 0) ? 0.70710678118654752440f : 1.0f;
        float avf = (c == 0) ? 0.70710678118654752440f : 1.0f;
        float a2    = auf * avf;          // ALPHA2 = np.outer in fp32
        float scale = a2 * 0.25f;         // _SCALE (exact *0.25)
        float dct   = scale * acc2;
        float xq    = dct / qt;           // IEEE fp32 divide
        float rd    = rintf(xq);          // np.round: half-to-even
        float d     = xq - rd;
        float cube  = (d * d) * d;        // post-round; fp32
        float q     = rd + cube;
        float deq   = q * qt;
        bufG[wid][lane] = deq * a2;       // G[u*8+v]
    }

    // ---- P4: IDCT stage 1 (relaxed): T2[x][v] = sum_u G[u][v]*A[u][x]
    {
        float acc3 = 0.f;
#pragma unroll
        for (int u = 0; u < 8; ++u)
            acc3 = fmaf(bufG[wid][u * 8 + c], Au[u], acc3);
        bufI[wid][r * 8 + c] = acc3;      // overwrite T1 (done with it)
    }

    // ---- P5: IDCT stage 2: out[x][y] = 0.25*sum_v T2[x][v]*A[v][y] + 128
    {
        float4 lo = *(const float4*)&bufI[wid][r * 8];
        float4 hi = *(const float4*)&bufI[wid][r * 8 + 4];
        float s = lo.x * Av[0];
        s = fmaf(lo.y, Av[1], s);
        s = fmaf(lo.z, Av[2], s);
        s = fmaf(lo.w, Av[3], s);
        s = fmaf(hi.x, Av[4], s);
        s = fmaf(hi.y, Av[5], s);
        s = fmaf(hi.z, Av[6], s);
        s = fmaf(hi.w, Av[7], s);
        float ov = 0.25f * s + 128.f;
        if (wid < 4) {
            int qy = wid >> 1, qx = wid & 1;
            Yt[qy * 8 + r][qx * 8 + c] = ov;   // reuse Yt for y2
        } else {
            Cout[wid - 4][lane] = ov;          // cb2 / cr2
        }
    }
    __syncthreads();

    // ---- P6: upsample chroma, YCbCr->RGB (noblas, no fma), clip, /255
    if (tid < 256) {
        int pr = tid >> 4, pc = tid & 15;
        float y2  = Yt[pr][pc];
        int ci = (pr >> 1) * 8 + (pc >> 1);
        float cbm = Cout[0][ci] - 128.f;       // +SHIFT2, separate rn add
        float crm = Cout[1][ci] - 128.f;
        float rv = y2 + (crm * 1.402f);
        float gv = (y2 + (cbm * -0.344136f)) + (crm * -0.714136f);
        float bv = y2 + (cbm * 1.772f);
        rv = fminf(fmaxf(rv, 0.f), 255.f) / 255.f;
        gv = fminf(fmaxf(gv, 0.f), 255.f) / 255.f;
        bv = fminf(fmaxf(bv, 0.f), 255.f) / 255.f;
        size_t base = ((size_t)b * 3 * HH + (size_t)(h0 + pr)) * WW + (w0 + pc);
        out[base]                       = rv;
        out[base + (size_t)HH * WW]     = gv;
        out[base + 2 * (size_t)HH * WW] = bv;
    }
}

extern "C" void kernel_launch(void* const* d_in, const int* in_sizes, int n_in,
                              void* d_out, int out_size, void* d_ws, size_t ws_size,
                              hipStream_t stream)
{
    const float* x = (const float*)d_in[0];
    float* o = (float*)d_out;
    int batch = in_sizes[0] / (3 * HH * WW);       // 32
    int tiles = batch * (HH / 16) * (WW / 16);     // 32768
    init_basis<<<1, 64, 0, stream>>>();
    jpeg_fused<<<tiles, 384, 0, stream>>>(x, o);
}

// Round 9
// 53.624 us; speedup vs baseline: 1.3477x; 1.3477x over previous
//
#include <hip/hip_runtime.h>
#include <math.h>

#define HH 512
#define WW 512
#define LS 68   // LDS row stride (floats) for 64-wide planes: (68*r+c)%32 keeps <=2-way

__device__ __constant__ float YTAB[64] = {
    16,11,10,16,24,40,51,61,
    12,12,14,19,26,58,60,55,
    14,13,16,24,40,57,69,56,
    14,17,22,29,51,87,80,62,
    18,22,37,56,68,109,103,77,
    24,35,55,64,81,104,113,92,
    49,64,78,87,103,121,120,101,
    72,92,95,98,112,100,103,99};
__device__ __constant__ float CTAB[64] = {
    17,18,24,47,99,99,99,99,
    18,21,26,66,99,99,99,99,
    24,26,56,99,99,99,99,99,
    47,66,99,99,99,99,99,99,
    99,99,99,99,99,99,99,99,
    99,99,99,99,99,99,99,99,
    99,99,99,99,99,99,99,99,
    99,99,99,99,99,99,99,99};

// One workgroup = 64x16 pixel region = 4 16x16 tiles = 16 Y + 4 Cb + 4 Cr
// 8x8-blocks. 512 threads / 8 waves; each wave runs exactly 3 DCT pipelines
// (2 Y + 1 chroma). All-thread float2 global I/O; raw RGB staged in LDS and
// converted in-place. Pre-round arithmetic is bit-identical to the verified
// R8 kernel: no-fma left-assoc color, paired 2x2 mean, ascending-k fmaf-chain
// pairwise einsum (BLAS sgemm semantics), IEEE div + rintf half-even.
__global__ __launch_bounds__(512) void jpeg_fused(const float* __restrict__ in,
                                                  float* __restrict__ out)
{
#pragma clang fp contract(off)
    __shared__ float P0s[3][16][LS];   // raw r/g/b -> in-place (y-128)/(cb+128)/(cr+128) -> final rgb path reads
    __shared__ float Ab[64];           // basis A[x][u], fp32 (np-exact)
    __shared__ float bufX[8][64];      // per-wave X block
    __shared__ __align__(16) float bufI[8][64]; // per-wave T1 / IDCT temp
    __shared__ float bufG[8][64];      // per-wave deq*alpha2
    __shared__ float Cout[8][64];      // [0..3]=Cb2 per tile, [4..7]=Cr2 per tile

    const int tid  = threadIdx.x;
    const int wid  = tid >> 6;
    const int lane = tid & 63;
    const int r    = lane >> 3;
    const int c    = lane & 7;

    const int bid = blockIdx.x;
    const int b   = bid >> 8;          // 256 blocks per image (32 rows x 8 cols)
    const int th  = (bid >> 3) & 31;
    const int tw  = bid & 7;
    const int h0  = th * 16;
    const int w0  = tw * 64;

    const size_t plane = (size_t)HH * WW;

    // ---- basis (np-exact: int mult, fp64 pi-mult/div, fp64 cos, fp32 cast)
    if (tid < 64) {
        int x = tid >> 3, u = tid & 7;
        double arg = (double)((2 * x + 1) * u) * 3.14159265358979323846 / 16.0;
        Ab[tid] = (float)cos(arg);
    }

    // ---- P0: load raw RGB, float2 x 3 per thread (fully coalesced, all threads)
    {
        int pr  = tid >> 5;            // 0..15
        int pc0 = (tid & 31) * 2;      // 0..62 even
        size_t base = ((size_t)b * 3 * HH + (size_t)(h0 + pr)) * WW + (w0 + pc0);
        float2 v0 = *(const float2*)(in + base);
        float2 v1 = *(const float2*)(in + base + plane);
        float2 v2 = *(const float2*)(in + base + 2 * plane);
        *(float2*)&P0s[0][pr][pc0] = v0;
        *(float2*)&P0s[1][pr][pc0] = v1;
        *(float2*)&P0s[2][pr][pc0] = v2;
    }
    __syncthreads();

    // ---- P0b: RGB -> YCbCr in place (2 pixels/thread; pixel-local so no race)
    {
        int pr  = tid >> 5;
        int pc0 = (tid & 31) * 2;
        float2 R2 = *(const float2*)&P0s[0][pr][pc0];
        float2 G2 = *(const float2*)&P0s[1][pr][pc0];
        float2 B2 = *(const float2*)&P0s[2][pr][pc0];
        float yv[2], cbv[2], crv[2];
        float rr[2] = {R2.x, R2.y}, gg[2] = {G2.x, G2.y}, bb[2] = {B2.x, B2.y};
#pragma unroll
        for (int j = 0; j < 2; ++j) {
            float rv = fminf(fmaxf(rr[j], 0.f), 1.f) * 255.f;
            float gv = fminf(fmaxf(gg[j], 0.f), 1.f) * 255.f;
            float bv = fminf(fmaxf(bb[j], 0.f), 1.f) * 255.f;
            // noblas matmul: left-assoc, each mul/add rounds separately (no fma)
            float y  = ((rv * 0.299f)     + (gv * 0.587f))     + (bv * 0.114f);
            float cb = ((rv * -0.168736f) + (gv * -0.331264f)) + (bv * 0.5f);
            float cr = ((rv * 0.5f)       + (gv * -0.418688f)) + (bv * -0.081312f);
            cb = cb + 128.f;             // +SHIFT1, separate rn add
            cr = cr + 128.f;
            yv[j]  = y - 128.f;          // channel does blocks-128
            cbv[j] = cb;
            crv[j] = cr;
        }
        *(float2*)&P0s[0][pr][pc0] = make_float2(yv[0], yv[1]);
        *(float2*)&P0s[1][pr][pc0] = make_float2(cbv[0], cbv[1]);
        *(float2*)&P0s[2][pr][pc0] = make_float2(crv[0], crv[1]);
    }
    __syncthreads();

    // per-lane basis columns: Au[k]=A[k][r], Av[k]=A[k][c]
    float Au[8], Av[8];
#pragma unroll
    for (int k = 0; k < 8; ++k) { Au[k] = Ab[k * 8 + r]; Av[k] = Ab[k * 8 + c]; }

    // ---- 3 DCT/quant/IDCT pipelines per wave (blocks: wid, wid+8, wid+16)
#pragma unroll
    for (int it = 0; it < 3; ++it) {
        const int blk = wid + 8 * it;       // 0..23
        float qtv, xv;
        int tile = 0, qy = 0, qx = 0;
        if (blk < 16) {
            tile = blk >> 2;
            qy = (blk & 3) >> 1;
            qx = blk & 1;
            xv = P0s[0][qy * 8 + r][tile * 16 + qx * 8 + c];
            qtv = YTAB[lane];
        } else {
            const int isCr = (blk >= 20);
            tile = blk - (isCr ? 20 : 16);
            const float (*Cs)[LS] = isCr ? P0s[2] : P0s[1];
            const int off = tile * 16;
            float p00 = Cs[2 * r][off + 2 * c],     p01 = Cs[2 * r][off + 2 * c + 1];
            float p10 = Cs[2 * r + 1][off + 2 * c], p11 = Cs[2 * r + 1][off + 2 * c + 1];
            float s01 = p00 + p01;           // paired association (np reduce)
            float s23 = p10 + p11;
            xv = (s01 + s23) / 4.0f - 128.f;
            qtv = CTAB[lane];
        }
        bufX[wid][lane] = xv;
        // sgemm pass 1 (contract x): T1[y,u], lane (y=r,u=c); fmaf chain from 0
        {
            float acc = 0.f;
#pragma unroll
            for (int x = 0; x < 8; ++x)
                acc = fmaf(bufX[wid][x * 8 + r], Av[x], acc);
            bufI[wid][r * 8 + c] = acc;      // T1[y*8+u], fp32
        }
        // sgemm pass 2 (contract y): raw[u,v], lane (u=r,v=c)
        float acc2 = 0.f;
#pragma unroll
        for (int y = 0; y < 8; ++y)
            acc2 = fmaf(bufI[wid][y * 8 + r], Av[y], acc2);
        // quantize (bit-critical through rintf), dequant
        {
            float auf = (r == 0) ? 0.70710678118654752440f : 1.0f;
            float avf = (c == 0) ? 0.70710678118654752440f : 1.0f;
            float a2    = auf * avf;         // ALPHA2 = np.outer in fp32
            float scale = a2 * 0.25f;        // _SCALE (exact *0.25)
            float dct   = scale * acc2;
            float xq    = dct / qtv;         // IEEE fp32 divide
            float rd    = rintf(xq);         // np.round: half-to-even
            float d     = xq - rd;
            float cube  = (d * d) * d;       // post-round
            float q     = rd + cube;
            float deq   = q * qtv;
            bufG[wid][lane] = deq * a2;      // G[u*8+v]
        }
        // IDCT stage 1 (relaxed): T2[x][v] = sum_u G[u][v]*A[u][x]
        {
            float acc3 = 0.f;
#pragma unroll
            for (int u = 0; u < 8; ++u)
                acc3 = fmaf(bufG[wid][u * 8 + c], Au[u], acc3);
            bufI[wid][r * 8 + c] = acc3;
        }
        // IDCT stage 2: out[x][y] = 0.25*sum_v T2[x][v]*A[v][y] + 128
        {
            float4 lo = *(const float4*)&bufI[wid][r * 8];
            float4 hi = *(const float4*)&bufI[wid][r * 8 + 4];
            float s = lo.x * Av[0];
            s = fmaf(lo.y, Av[1], s);
            s = fmaf(lo.z, Av[2], s);
            s = fmaf(lo.w, Av[3], s);
            s = fmaf(hi.x, Av[4], s);
            s = fmaf(hi.y, Av[5], s);
            s = fmaf(hi.z, Av[6], s);
            s = fmaf(hi.w, Av[7], s);
            float ov = 0.25f * s + 128.f;
            if (blk < 16) {
                // y2 back over the y-plane; region owned by this pipeline only
                P0s[0][qy * 8 + r][tile * 16 + qx * 8 + c] = ov;
            } else {
                Cout[blk - 16][lane] = ov;   // Cb2 tiles 0..3, Cr2 tiles 4..7
            }
        }
    }
    __syncthreads();

    // ---- P6: upsample chroma, YCbCr->RGB (no fma), clip, /255, float2 stores
    {
        int pr  = tid >> 5;
        int pc0 = (tid & 31) * 2;          // even; pair shares tile AND chroma cell
        float2 y2 = *(const float2*)&P0s[0][pr][pc0];
        int tile = pc0 >> 4;
        int cy = pr >> 1, cx = (pc0 & 15) >> 1;
        float cbm = Cout[tile][cy * 8 + cx] - 128.f;       // +SHIFT2 separate add
        float crm = Cout[4 + tile][cy * 8 + cx] - 128.f;
        float outv[3][2];
        float yy[2] = {y2.x, y2.y};
#pragma unroll
        for (int j = 0; j < 2; ++j) {
            float rv = yy[j] + (crm * 1.402f);
            float gv = (yy[j] + (cbm * -0.344136f)) + (crm * -0.714136f);
            float bv = yy[j] + (cbm * 1.772f);
            outv[0][j] = fminf(fmaxf(rv, 0.f), 255.f) / 255.f;
            outv[1][j] = fminf(fmaxf(gv, 0.f), 255.f) / 255.f;
            outv[2][j] = fminf(fmaxf(bv, 0.f), 255.f) / 255.f;
        }
        size_t base = ((size_t)b * 3 * HH + (size_t)(h0 + pr)) * WW + (w0 + pc0);
        *(float2*)(out + base)             = make_float2(outv[0][0], outv[0][1]);
        *(float2*)(out + base + plane)     = make_float2(outv[1][0], outv[1][1]);
        *(float2*)(out + base + 2 * plane) = make_float2(outv[2][0], outv[2][1]);
    }
}

extern "C" void kernel_launch(void* const* d_in, const int* in_sizes, int n_in,
                              void* d_out, int out_size, void* d_ws, size_t ws_size,
                              hipStream_t stream)
{
    const float* x = (const float*)d_in[0];
    float* o = (float*)d_out;
    int batch  = in_sizes[0] / (3 * HH * WW);        // 32
    int blocks = batch * (HH / 16) * (WW / 64);      // 32*32*8 = 8192
    jpeg_fused<<<blocks, 512, 0, stream>>>(x, o);
}

// Round 10
// 53.429 us; speedup vs baseline: 1.3526x; 1.0037x over previous
//
#include <hip/hip_runtime.h>
#include <math.h>

#define HH 512
#define WW 512
#define LS 68   // LDS row stride (floats) for 64-wide planes: (68*r+c)%32 keeps <=2-way

__device__ __constant__ float YTAB[64] = {
    16,11,10,16,24,40,51,61,
    12,12,14,19,26,58,60,55,
    14,13,16,24,40,57,69,56,
    14,17,22,29,51,87,80,62,
    18,22,37,56,68,109,103,77,
    24,35,55,64,81,104,113,92,
    49,64,78,87,103,121,120,101,
    72,92,95,98,112,100,103,99};
__device__ __constant__ float CTAB[64] = {
    17,18,24,47,99,99,99,99,
    18,21,26,66,99,99,99,99,
    24,26,56,99,99,99,99,99,
    47,66,99,99,99,99,99,99,
    99,99,99,99,99,99,99,99,
    99,99,99,99,99,99,99,99,
    99,99,99,99,99,99,99,99,
    99,99,99,99,99,99,99,99};

// One workgroup = 64x16 pixel region = 4 16x16 tiles = 16 Y + 4 Cb + 4 Cr
// 8x8-blocks. 512 threads / 8 waves; each wave runs exactly 3 DCT pipelines
// (2 Y + 1 chroma). All-thread float2 global I/O; raw RGB staged in LDS and
// converted in-place. Pre-round arithmetic is bit-identical to the verified
// R8 kernel: no-fma left-assoc color, paired 2x2 mean, ascending-k fmaf-chain
// pairwise einsum (BLAS sgemm semantics), IEEE div + rintf half-even.
__global__ __launch_bounds__(512) void jpeg_fused(const float* __restrict__ in,
                                                  float* __restrict__ out)
{
#pragma clang fp contract(off)
    __shared__ float P0s[3][16][LS];   // raw r/g/b -> in-place (y-128)/(cb+128)/(cr+128) -> final rgb path reads
    __shared__ float Ab[64];           // basis A[x][u], fp32 (np-exact)
    __shared__ float bufX[8][64];      // per-wave X block
    __shared__ __align__(16) float bufI[8][64]; // per-wave T1 / IDCT temp
    __shared__ float bufG[8][64];      // per-wave deq*alpha2
    __shared__ float Cout[8][64];      // [0..3]=Cb2 per tile, [4..7]=Cr2 per tile

    const int tid  = threadIdx.x;
    const int wid  = tid >> 6;
    const int lane = tid & 63;
    const int r    = lane >> 3;
    const int c    = lane & 7;

    const int bid = blockIdx.x;
    const int b   = bid >> 8;          // 256 blocks per image (32 rows x 8 cols)
    const int th  = (bid >> 3) & 31;
    const int tw  = bid & 7;
    const int h0  = th * 16;
    const int w0  = tw * 64;

    const size_t plane = (size_t)HH * WW;

    // ---- basis (np-exact: int mult, fp64 pi-mult/div, fp64 cos, fp32 cast)
    if (tid < 64) {
        int x = tid >> 3, u = tid & 7;
        double arg = (double)((2 * x + 1) * u) * 3.14159265358979323846 / 16.0;
        Ab[tid] = (float)cos(arg);
    }

    // ---- P0: load raw RGB, float2 x 3 per thread (fully coalesced, all threads)
    {
        int pr  = tid >> 5;            // 0..15
        int pc0 = (tid & 31) * 2;      // 0..62 even
        size_t base = ((size_t)b * 3 * HH + (size_t)(h0 + pr)) * WW + (w0 + pc0);
        float2 v0 = *(const float2*)(in + base);
        float2 v1 = *(const float2*)(in + base + plane);
        float2 v2 = *(const float2*)(in + base + 2 * plane);
        *(float2*)&P0s[0][pr][pc0] = v0;
        *(float2*)&P0s[1][pr][pc0] = v1;
        *(float2*)&P0s[2][pr][pc0] = v2;
    }
    __syncthreads();

    // ---- P0b: RGB -> YCbCr in place (2 pixels/thread; pixel-local so no race)
    {
        int pr  = tid >> 5;
        int pc0 = (tid & 31) * 2;
        float2 R2 = *(const float2*)&P0s[0][pr][pc0];
        float2 G2 = *(const float2*)&P0s[1][pr][pc0];
        float2 B2 = *(const float2*)&P0s[2][pr][pc0];
        float yv[2], cbv[2], crv[2];
        float rr[2] = {R2.x, R2.y}, gg[2] = {G2.x, G2.y}, bb[2] = {B2.x, B2.y};
#pragma unroll
        for (int j = 0; j < 2; ++j) {
            float rv = fminf(fmaxf(rr[j], 0.f), 1.f) * 255.f;
            float gv = fminf(fmaxf(gg[j], 0.f), 1.f) * 255.f;
            float bv = fminf(fmaxf(bb[j], 0.f), 1.f) * 255.f;
            // noblas matmul: left-assoc, each mul/add rounds separately (no fma)
            float y  = ((rv * 0.299f)     + (gv * 0.587f))     + (bv * 0.114f);
            float cb = ((rv * -0.168736f) + (gv * -0.331264f)) + (bv * 0.5f);
            float cr = ((rv * 0.5f)       + (gv * -0.418688f)) + (bv * -0.081312f);
            cb = cb + 128.f;             // +SHIFT1, separate rn add
            cr = cr + 128.f;
            yv[j]  = y - 128.f;          // channel does blocks-128
            cbv[j] = cb;
            crv[j] = cr;
        }
        *(float2*)&P0s[0][pr][pc0] = make_float2(yv[0], yv[1]);
        *(float2*)&P0s[1][pr][pc0] = make_float2(cbv[0], cbv[1]);
        *(float2*)&P0s[2][pr][pc0] = make_float2(crv[0], crv[1]);
    }
    __syncthreads();

    // per-lane basis columns: Au[k]=A[k][r], Av[k]=A[k][c]
    float Au[8], Av[8];
#pragma unroll
    for (int k = 0; k < 8; ++k) { Au[k] = Ab[k * 8 + r]; Av[k] = Ab[k * 8 + c]; }

    // ---- 3 DCT/quant/IDCT pipelines per wave (blocks: wid, wid+8, wid+16)
#pragma unroll
    for (int it = 0; it < 3; ++it) {
        const int blk = wid + 8 * it;       // 0..23
        float qtv, xv;
        int tile = 0, qy = 0, qx = 0;
        if (blk < 16) {
            tile = blk >> 2;
            qy = (blk & 3) >> 1;
            qx = blk & 1;
            xv = P0s[0][qy * 8 + r][tile * 16 + qx * 8 + c];
            qtv = YTAB[lane];
        } else {
            const int isCr = (blk >= 20);
            tile = blk - (isCr ? 20 : 16);
            const float (*Cs)[LS] = isCr ? P0s[2] : P0s[1];
            const int off = tile * 16;
            float p00 = Cs[2 * r][off + 2 * c],     p01 = Cs[2 * r][off + 2 * c + 1];
            float p10 = Cs[2 * r + 1][off + 2 * c], p11 = Cs[2 * r + 1][off + 2 * c + 1];
            float s01 = p00 + p01;           // paired association (np reduce)
            float s23 = p10 + p11;
            xv = (s01 + s23) / 4.0f - 128.f;
            qtv = CTAB[lane];
        }
        bufX[wid][lane] = xv;
        // sgemm pass 1 (contract x): T1[y,u], lane (y=r,u=c); fmaf chain from 0
        {
            float acc = 0.f;
#pragma unroll
            for (int x = 0; x < 8; ++x)
                acc = fmaf(bufX[wid][x * 8 + r], Av[x], acc);
            bufI[wid][r * 8 + c] = acc;      // T1[y*8+u], fp32
        }
        // sgemm pass 2 (contract y): raw[u,v], lane (u=r,v=c)
        float acc2 = 0.f;
#pragma unroll
        for (int y = 0; y < 8; ++y)
            acc2 = fmaf(bufI[wid][y * 8 + r], Av[y], acc2);
        // quantize (bit-critical through rintf), dequant
        {
            float auf = (r == 0) ? 0.70710678118654752440f : 1.0f;
            float avf = (c == 0) ? 0.70710678118654752440f : 1.0f;
            float a2    = auf * avf;         // ALPHA2 = np.outer in fp32
            float scale = a2 * 0.25f;        // _SCALE (exact *0.25)
            float dct   = scale * acc2;
            float xq    = dct / qtv;         // IEEE fp32 divide
            float rd    = rintf(xq);         // np.round: half-to-even
            float d     = xq - rd;
            float cube  = (d * d) * d;       // post-round
            float q     = rd + cube;
            float deq   = q * qtv;
            bufG[wid][lane] = deq * a2;      // G[u*8+v]
        }
        // IDCT stage 1 (relaxed): T2[x][v] = sum_u G[u][v]*A[u][x]
        {
            float acc3 = 0.f;
#pragma unroll
            for (int u = 0; u < 8; ++u)
                acc3 = fmaf(bufG[wid][u * 8 + c], Au[u], acc3);
            bufI[wid][r * 8 + c] = acc3;
        }
        // IDCT stage 2: out[x][y] = 0.25*sum_v T2[x][v]*A[v][y] + 128
        {
            float4 lo = *(const float4*)&bufI[wid][r * 8];
            float4 hi = *(const float4*)&bufI[wid][r * 8 + 4];
            float s = lo.x * Av[0];
            s = fmaf(lo.y, Av[1], s);
            s = fmaf(lo.z, Av[2], s);
            s = fmaf(lo.w, Av[3], s);
            s = fmaf(hi.x, Av[4], s);
            s = fmaf(hi.y, Av[5], s);
            s = fmaf(hi.z, Av[6], s);
            s = fmaf(hi.w, Av[7], s);
            float ov = 0.25f * s + 128.f;
            if (blk < 16) {
                // y2 back over the y-plane; region owned by this pipeline only
                P0s[0][qy * 8 + r][tile * 16 + qx * 8 + c] = ov;
            } else {
                Cout[blk - 16][lane] = ov;   // Cb2 tiles 0..3, Cr2 tiles 4..7
            }
        }
    }
    __syncthreads();

    // ---- P6: upsample chroma, YCbCr->RGB (no fma), clip, /255, float2 stores
    {
        int pr  = tid >> 5;
        int pc0 = (tid & 31) * 2;          // even; pair shares tile AND chroma cell
        float2 y2 = *(const float2*)&P0s[0][pr][pc0];
        int tile = pc0 >> 4;
        int cy = pr >> 1, cx = (pc0 & 15) >> 1;
        float cbm = Cout[tile][cy * 8 + cx] - 128.f;       // +SHIFT2 separate add
        float crm = Cout[4 + tile][cy * 8 + cx] - 128.f;
        float outv[3][2];
        float yy[2] = {y2.x, y2.y};
#pragma unroll
        for (int j = 0; j < 2; ++j) {
            float rv = yy[j] + (crm * 1.402f);
            float gv = (yy[j] + (cbm * -0.344136f)) + (crm * -0.714136f);
            float bv = yy[j] + (cbm * 1.772f);
            outv[0][j] = fminf(fmaxf(rv, 0.f), 255.f) / 255.f;
            outv[1][j] = fminf(fmaxf(gv, 0.f), 255.f) / 255.f;
            outv[2][j] = fminf(fmaxf(bv, 0.f), 255.f) / 255.f;
        }
        size_t base = ((size_t)b * 3 * HH + (size_t)(h0 + pr)) * WW + (w0 + pc0);
        *(float2*)(out + base)             = make_float2(outv[0][0], outv[0][1]);
        *(float2*)(out + base + plane)     = make_float2(outv[1][0], outv[1][1]);
        *(float2*)(out + base + 2 * plane) = make_float2(outv[2][0], outv[2][1]);
    }
}

extern "C" void kernel_launch(void* const* d_in, const int* in_sizes, int n_in,
                              void* d_out, int out_size, void* d_ws, size_t ws_size,
                              hipStream_t stream)
{
    const float* x = (const float*)d_in[0];
    float* o = (float*)d_out;
    int batch  = in_sizes[0] / (3 * HH * WW);        // 32
    int blocks = batch * (HH / 16) * (WW / 64);      // 32*32*8 = 8192
    jpeg_fused<<<blocks, 512, 0, stream>>>(x, o);
}

// Round 11
// 52.558 us; speedup vs baseline: 1.3750x; 1.0166x over previous
//
#include <hip/hip_runtime.h>
#include <math.h>

#define HH 512
#define WW 512
#define YS 132   // Y plane row stride (words); 132%32=4 -> spread banks
#define CS 68    // chroma plane row stride
#define SG 68    // scratch group stride (words); 68%32=4

__device__ __constant__ float YTAB[64] = {
    16,11,10,16,24,40,51,61,
    12,12,14,19,26,58,60,55,
    14,13,16,24,40,57,69,56,
    14,17,22,29,51,87,80,62,
    18,22,37,56,68,109,103,77,
    24,35,55,64,81,104,113,92,
    49,64,78,87,103,121,120,101,
    72,92,95,98,112,100,103,99};
__device__ __constant__ float CTAB[64] = {
    17,18,24,47,99,99,99,99,
    18,21,26,66,99,99,99,99,
    24,26,56,99,99,99,99,99,
    47,66,99,99,99,99,99,99,
    99,99,99,99,99,99,99,99,
    99,99,99,99,99,99,99,99,
    99,99,99,99,99,99,99,99,
    99,99,99,99,99,99,99,99};

// One workgroup = 128x16 pixel region = 8 tiles = 32 Y + 8 Cb + 8 Cr blocks.
// 384 threads / 6 waves; each wave owns 8 blocks SIMULTANEOUSLY (8 lanes per
// block, lane j holds column j in registers). Waves 0-3: Y, wave 4: Cb,
// wave 5: Cr. All four 8x8 matrix passes are in-register fmaf chains with the
// basis in SGPRs (readfirstlane); only 3 LDS transposes per wave remain.
// Bit-critical pre-round math identical to the verified R8/R10 kernels:
//  - color: left-assoc mul/add, NO fma; chroma mean paired (s01+s23)/4
//  - DCT: two ascending-k fmaf chains (BLAS sgemm semantics), fp32 T1
//  - quantize: IEEE fp32 div, rintf (half-even), cube in fp32
__global__ __launch_bounds__(384) void jpeg_fused(const float* __restrict__ in,
                                                  float* __restrict__ out)
{
#pragma clang fp contract(off)
    __shared__ float Yp[16][YS];       // y-128 staged; y2 written back in place
    __shared__ float Cbp[8][CS];       // downsampled cb (+128); cb2 in place
    __shared__ float Crp[8][CS];       // downsampled cr (+128); cr2 in place
    __shared__ float Ab[64];           // basis A[x][u] (np-exact)
    __shared__ float QY[64], QC[64];   // quant tables
    __shared__ float Scr[6][8 * SG];   // per-wave transpose scratch

    const int tid  = threadIdx.x;
    const int wid  = tid >> 6;
    const int lane = tid & 63;
    const int g    = lane >> 3;        // block-group within wave
    const int j    = lane & 7;         // role index within block

    const int bid   = blockIdx.x;
    const int b     = bid >> 7;        // 128 WGs per image (32 strips x 4 cols)
    const int strip = (bid >> 2) & 31;
    const int rcol  = bid & 3;
    const int h0    = strip * 16;
    const int w0    = rcol * 128;
    const size_t plane = (size_t)HH * WW;

    // ---- init: basis (np-exact: int mult, fp64 pi-mult/div, fp64 cos, fp32
    // cast) + quant tables into LDS
    if (tid < 64) {
        int x = tid >> 3, u = tid & 7;
        double arg = (double)((2 * x + 1) * u) * 3.14159265358979323846 / 16.0;
        Ab[tid] = (float)cos(arg);
        QY[tid] = YTAB[tid];
        QC[tid] = CTAB[tid];
    }

    // ---- staging: each thread handles 2x2 pixel quads; converts in regs,
    // writes y-128 plane + downsampled chroma (no full-res chroma staging)
    for (int q = tid; q < 512; q += 384) {
        int qr = q >> 6, qc = q & 63;
        int pr = 2 * qr, pc = 2 * qc;
        size_t base = ((size_t)b * 3 * HH + (size_t)(h0 + pr)) * WW + (w0 + pc);
        float2 r0 = *(const float2*)(in + base);
        float2 r1 = *(const float2*)(in + base + WW);
        float2 g0 = *(const float2*)(in + base + plane);
        float2 g1 = *(const float2*)(in + base + plane + WW);
        float2 b0 = *(const float2*)(in + base + 2 * plane);
        float2 b1 = *(const float2*)(in + base + 2 * plane + WW);
        float rr[4] = {r0.x, r0.y, r1.x, r1.y};
        float gg[4] = {g0.x, g0.y, g1.x, g1.y};
        float bb[4] = {b0.x, b0.y, b1.x, b1.y};
        float yv[4], cbv[4], crv[4];
#pragma unroll
        for (int k = 0; k < 4; ++k) {
            float rv = fminf(fmaxf(rr[k], 0.f), 1.f) * 255.f;
            float gv = fminf(fmaxf(gg[k], 0.f), 1.f) * 255.f;
            float bv = fminf(fmaxf(bb[k], 0.f), 1.f) * 255.f;
            // noblas matmul: left-assoc, separate rn mul/add (no fma)
            float y  = ((rv * 0.299f)     + (gv * 0.587f))     + (bv * 0.114f);
            float cb = ((rv * -0.168736f) + (gv * -0.331264f)) + (bv * 0.5f);
            float cr = ((rv * 0.5f)       + (gv * -0.418688f)) + (bv * -0.081312f);
            yv[k]  = y - 128.f;          // (y+0) then blocks-128
            cbv[k] = cb + 128.f;         // +SHIFT1 separate add
            crv[k] = cr + 128.f;
        }
        *(float2*)&Yp[pr][pc]     = make_float2(yv[0], yv[1]);
        *(float2*)&Yp[pr + 1][pc] = make_float2(yv[2], yv[3]);
        // np multi-axis mean: paired (p00+p01)+(p10+p11), true-div by 4
        float s01 = cbv[0] + cbv[1], s23 = cbv[2] + cbv[3];
        Cbp[qr][qc] = (s01 + s23) / 4.0f;
        float t01 = crv[0] + crv[1], t23 = crv[2] + crv[3];
        Crp[qr][qc] = (t01 + t23) / 4.0f;
    }
    __syncthreads();

    // ---- basis -> SGPRs (wave-uniform scalars; frees VALU/LDS in the chains)
    float As[64];
#pragma unroll
    for (int i = 0; i < 64; ++i)
        As[i] = __int_as_float(__builtin_amdgcn_readfirstlane(__float_as_int(Ab[i])));

    const bool isY = (wid < 4);
    float* scr = &Scr[wid][0];

    // ---- load X columns into registers (lane j = column j of its block)
    float X[8];
    if (isY) {
        int blk = wid * 8 + g;         // 0..31 over 2x16 Y-block grid
        int by = blk >> 4, bx = blk & 15;
#pragma unroll
        for (int x = 0; x < 8; ++x) X[x] = Yp[by * 8 + x][bx * 8 + j];
    } else {
        const float (*Cp)[CS] = (wid == 4) ? Cbp : Crp;
#pragma unroll
        for (int x = 0; x < 8; ++x) X[x] = Cp[x][g * 8 + j] - 128.f;
    }

    // ---- pass1 (contract x): T1[y=j][u], ascending-x fmaf chain from 0
    float T[8];
#pragma unroll
    for (int u = 0; u < 8; ++u) {
        float a = 0.f;
#pragma unroll
        for (int x = 0; x < 8; ++x) a = fmaf(X[x], As[x * 8 + u], a);
        T[u] = a;
    }
    // transpose: scatter T1[j][u] -> scr slot (u, j); read row u=j back
#pragma unroll
    for (int u = 0; u < 8; ++u) scr[g * SG + u * 8 + j] = T[u];
    float Tt[8];
    {
        float4 a = *(const float4*)&scr[g * SG + j * 8];
        float4 c = *(const float4*)&scr[g * SG + j * 8 + 4];
        Tt[0] = a.x; Tt[1] = a.y; Tt[2] = a.z; Tt[3] = a.w;
        Tt[4] = c.x; Tt[5] = c.y; Tt[6] = c.z; Tt[7] = c.w;
    }

    // ---- pass2 (contract y): raw[u=j][v], ascending-y fmaf chain from 0
    float R[8];
#pragma unroll
    for (int v = 0; v < 8; ++v) {
        float a = 0.f;
#pragma unroll
        for (int y = 0; y < 8; ++y) a = fmaf(Tt[y], As[y * 8 + v], a);
        R[v] = a;
    }

    // ---- quantize row u=j (bit-critical through rintf), dequant, *alpha2
    float qt[8];
    {
        const float* QT = isY ? QY : QC;
        float4 a = *(const float4*)&QT[j * 8];
        float4 c = *(const float4*)&QT[j * 8 + 4];
        qt[0] = a.x; qt[1] = a.y; qt[2] = a.z; qt[3] = a.w;
        qt[4] = c.x; qt[5] = c.y; qt[6] = c.z; qt[7] = c.w;
    }
    const float RC = 0.70710678118654752440f;
    float au = (j == 0) ? RC : 1.0f;
    float G[8];
#pragma unroll
    for (int v = 0; v < 8; ++v) {
        float av    = (v == 0) ? RC : 1.0f;   // compile-time per v
        float a2    = au * av;                // ALPHA2 fp32 product
        float scale = a2 * 0.25f;             // _SCALE
        float dct   = scale * R[v];
        float xq    = dct / qt[v];            // IEEE fp32 divide
        float rd    = rintf(xq);              // half-to-even
        float d     = xq - rd;
        float cube  = (d * d) * d;
        float qq    = rd + cube;
        float deq   = qq * qt[v];
        G[v] = deq * a2;
    }
    // transpose G (row u=j -> col v=j)
#pragma unroll
    for (int v = 0; v < 8; ++v) scr[g * SG + v * 8 + j] = G[v];
    float Gt[8];
    {
        float4 a = *(const float4*)&scr[g * SG + j * 8];
        float4 c = *(const float4*)&scr[g * SG + j * 8 + 4];
        Gt[0] = a.x; Gt[1] = a.y; Gt[2] = a.z; Gt[3] = a.w;
        Gt[4] = c.x; Gt[5] = c.y; Gt[6] = c.z; Gt[7] = c.w;
    }

    // ---- IDCT pass1 (contract u): T2[x][v=j]
    float T2[8];
#pragma unroll
    for (int x = 0; x < 8; ++x) {
        float a = 0.f;
#pragma unroll
        for (int u = 0; u < 8; ++u) a = fmaf(Gt[u], As[u * 8 + x], a);
        T2[x] = a;
    }
    // transpose T2 (col v=j -> row x=j)
#pragma unroll
    for (int x = 0; x < 8; ++x) scr[g * SG + x * 8 + j] = T2[x];
    float T2t[8];
    {
        float4 a = *(const float4*)&scr[g * SG + j * 8];
        float4 c = *(const float4*)&scr[g * SG + j * 8 + 4];
        T2t[0] = a.x; T2t[1] = a.y; T2t[2] = a.z; T2t[3] = a.w;
        T2t[4] = c.x; T2t[5] = c.y; T2t[6] = c.z; T2t[7] = c.w;
    }

    // ---- IDCT pass2 (contract v): out[x=j][y] = 0.25*sum + 128
    float O[8];
#pragma unroll
    for (int y = 0; y < 8; ++y) {
        float a = 0.f;
#pragma unroll
        for (int v = 0; v < 8; ++v) a = fmaf(T2t[v], As[v * 8 + y], a);
        O[y] = 0.25f * a + 128.f;
    }

    // ---- write back (in place; block regions disjoint per wave)
    if (isY) {
        int blk = wid * 8 + g;
        int by = blk >> 4, bx = blk & 15;
        *(float4*)&Yp[by * 8 + j][bx * 8]     = make_float4(O[0], O[1], O[2], O[3]);
        *(float4*)&Yp[by * 8 + j][bx * 8 + 4] = make_float4(O[4], O[5], O[6], O[7]);
    } else {
        float (*Cp)[CS] = (wid == 4) ? Cbp : Crp;
        *(float4*)&Cp[j][g * 8]     = make_float4(O[0], O[1], O[2], O[3]);
        *(float4*)&Cp[j][g * 8 + 4] = make_float4(O[4], O[5], O[6], O[7]);
    }
    __syncthreads();

    // ---- output: upsample chroma, YCbCr->RGB (no fma), clip, /255
    for (int q = tid; q < 512; q += 384) {
        int qr = q >> 6, qc = q & 63;
        int pr = 2 * qr, pc = 2 * qc;
        float2 ya = *(const float2*)&Yp[pr][pc];
        float2 yb = *(const float2*)&Yp[pr + 1][pc];
        float cbm = Cbp[qr][qc] - 128.f;     // +SHIFT2 separate add
        float crm = Crp[qr][qc] - 128.f;
        float yy[4] = {ya.x, ya.y, yb.x, yb.y};
        float ov[3][4];
#pragma unroll
        for (int k = 0; k < 4; ++k) {
            float rv = yy[k] + (crm * 1.402f);
            float gv = (yy[k] + (cbm * -0.344136f)) + (crm * -0.714136f);
            float bv = yy[k] + (cbm * 1.772f);
            ov[0][k] = fminf(fmaxf(rv, 0.f), 255.f) / 255.f;
            ov[1][k] = fminf(fmaxf(gv, 0.f), 255.f) / 255.f;
            ov[2][k] = fminf(fmaxf(bv, 0.f), 255.f) / 255.f;
        }
        size_t base = ((size_t)b * 3 * HH + (size_t)(h0 + pr)) * WW + (w0 + pc);
        *(float2*)(out + base)                  = make_float2(ov[0][0], ov[0][1]);
        *(float2*)(out + base + WW)             = make_float2(ov[0][2], ov[0][3]);
        *(float2*)(out + base + plane)          = make_float2(ov[1][0], ov[1][1]);
        *(float2*)(out + base + plane + WW)     = make_float2(ov[1][2], ov[1][3]);
        *(float2*)(out + base + 2 * plane)      = make_float2(ov[2][0], ov[2][1]);
        *(float2*)(out + base + 2 * plane + WW) = make_float2(ov[2][2], ov[2][3]);
    }
}

extern "C" void kernel_launch(void* const* d_in, const int* in_sizes, int n_in,
                              void* d_out, int out_size, void* d_ws, size_t ws_size,
                              hipStream_t stream)
{
    const float* x = (const float*)d_in[0];
    float* o = (float*)d_out;
    int batch  = in_sizes[0] / (3 * HH * WW);        // 32
    int blocks = batch * (HH / 16) * (WW / 128);     // 32*32*4 = 4096
    jpeg_fused<<<blocks, 384, 0, stream>>>(x, o);
}

// Round 12
// 41.812 us; speedup vs baseline: 1.7284x; 1.2570x over previous
//
#include <hip/hip_runtime.h>
#include <math.h>

#define HH 512
#define WW 512
#define YS 132   // Y plane row stride (words); 132%32=4 -> spread banks
#define CS 68    // chroma plane row stride
#define SG 68    // scratch group stride (words); 68%32=4

typedef float f4 __attribute__((ext_vector_type(4)));

__device__ __constant__ float YTAB[64] = {
    16,11,10,16,24,40,51,61,
    12,12,14,19,26,58,60,55,
    14,13,16,24,40,57,69,56,
    14,17,22,29,51,87,80,62,
    18,22,37,56,68,109,103,77,
    24,35,55,64,81,104,113,92,
    49,64,78,87,103,121,120,101,
    72,92,95,98,112,100,103,99};
__device__ __constant__ float CTAB[64] = {
    17,18,24,47,99,99,99,99,
    18,21,26,66,99,99,99,99,
    24,26,56,99,99,99,99,99,
    47,66,99,99,99,99,99,99,
    99,99,99,99,99,99,99,99,
    99,99,99,99,99,99,99,99,
    99,99,99,99,99,99,99,99,
    99,99,99,99,99,99,99,99};

// One workgroup = 128x16 pixel region = 32 Y + 8 Cb + 8 Cr blocks = 48 block
// groups = 6 waves x 8 groups. Lane j of a group holds column j of its 8x8
// block in registers; all 4 matrix passes are in-register fmaf chains with
// the basis in SGPRs; 3 small LDS transposes. Memory phases: 256 threads do
// 2row x 4col items with float4 I/O (16B/lane); output stores nontemporal.
// Bit-critical pre-round math identical to verified R8/R10/R11:
//  - color: left-assoc mul/add, NO fma; chroma mean paired (s01+s23)/4
//  - DCT: two ascending-k fmaf chains (BLAS sgemm semantics), fp32 T1
//  - quantize: IEEE fp32 div by qt, rintf (half-even), cube in fp32
// Post-round path is relaxed (fmaf, *INV255).
__global__ __launch_bounds__(384) void jpeg_fused(const float* __restrict__ in,
                                                  float* __restrict__ out)
{
#pragma clang fp contract(off)
    __shared__ float Yp[16][YS];       // y-128 staged; y2 written back in place
    __shared__ float Cbp[8][CS];       // downsampled cb (+128); cb2 in place
    __shared__ float Crp[8][CS];       // downsampled cr (+128); cr2 in place
    __shared__ float Ab[64];           // basis A[x][u] (np-exact)
    __shared__ float QY[64], QC[64];   // quant tables
    __shared__ float Scr[6][8 * SG];   // per-wave transpose scratch

    const int tid  = threadIdx.x;
    const int wid  = tid >> 6;
    const int lane = tid & 63;
    const int g    = lane >> 3;        // block-group within wave
    const int j    = lane & 7;         // role index within block

    const int bid   = blockIdx.x;
    const int b     = bid >> 7;        // 128 WGs per image (32 strips x 4 cols)
    const int strip = (bid >> 2) & 31;
    const int rcol  = bid & 3;
    const int h0    = strip * 16;
    const int w0    = rcol * 128;
    const size_t plane = (size_t)HH * WW;

    // ---- init: basis (np-exact: int mult, fp64 pi-mult/div, fp64 cos, fp32
    // cast) + quant tables into LDS
    if (tid < 64) {
        int x = tid >> 3, u = tid & 7;
        double arg = (double)((2 * x + 1) * u) * 3.14159265358979323846 / 16.0;
        Ab[tid] = (float)cos(arg);
        QY[tid] = YTAB[tid];
        QC[tid] = CTAB[tid];
    }

    // ---- staging: 256 threads x (2 rows x 4 cols) items, float4 loads;
    // converts in regs, writes y-128 plane + downsampled chroma
    if (tid < 256) {
        int rowp = tid >> 5;           // 0..7 (row pair)
        int pc   = (tid & 31) * 4;     // 0..124
        int pr   = rowp * 2;
        size_t base = ((size_t)b * 3 * HH + (size_t)(h0 + pr)) * WW + (w0 + pc);
        float4 r0 = *(const float4*)(in + base);
        float4 r1 = *(const float4*)(in + base + WW);
        float4 g0 = *(const float4*)(in + base + plane);
        float4 g1 = *(const float4*)(in + base + plane + WW);
        float4 b0 = *(const float4*)(in + base + 2 * plane);
        float4 b1 = *(const float4*)(in + base + 2 * plane + WW);
        float rr[8] = {r0.x, r0.y, r0.z, r0.w, r1.x, r1.y, r1.z, r1.w};
        float gg[8] = {g0.x, g0.y, g0.z, g0.w, g1.x, g1.y, g1.z, g1.w};
        float bb[8] = {b0.x, b0.y, b0.z, b0.w, b1.x, b1.y, b1.z, b1.w};
        float yv[8], cbv[8], crv[8];
#pragma unroll
        for (int k = 0; k < 8; ++k) {
            float rv = fminf(fmaxf(rr[k], 0.f), 1.f) * 255.f;
            float gv = fminf(fmaxf(gg[k], 0.f), 1.f) * 255.f;
            float bv = fminf(fmaxf(bb[k], 0.f), 1.f) * 255.f;
            // noblas matmul: left-assoc, separate rn mul/add (no fma)
            float y  = ((rv * 0.299f)     + (gv * 0.587f))     + (bv * 0.114f);
            float cb = ((rv * -0.168736f) + (gv * -0.331264f)) + (bv * 0.5f);
            float cr = ((rv * 0.5f)       + (gv * -0.418688f)) + (bv * -0.081312f);
            yv[k]  = y - 128.f;          // (y+0) then blocks-128
            cbv[k] = cb + 128.f;         // +SHIFT1 separate add
            crv[k] = cr + 128.f;
        }
        *(float4*)&Yp[pr][pc]     = make_float4(yv[0], yv[1], yv[2], yv[3]);
        *(float4*)&Yp[pr + 1][pc] = make_float4(yv[4], yv[5], yv[6], yv[7]);
        // np multi-axis mean: paired (p00+p01)+(p10+p11), true-div by 4
        int qc = (tid & 31) * 2;
        {
            float s01a = cbv[0] + cbv[1], s23a = cbv[4] + cbv[5];
            float s01b = cbv[2] + cbv[3], s23b = cbv[6] + cbv[7];
            *(float2*)&Cbp[rowp][qc] =
                make_float2((s01a + s23a) / 4.0f, (s01b + s23b) / 4.0f);
        }
        {
            float s01a = crv[0] + crv[1], s23a = crv[4] + crv[5];
            float s01b = crv[2] + crv[3], s23b = crv[6] + crv[7];
            *(float2*)&Crp[rowp][qc] =
                make_float2((s01a + s23a) / 4.0f, (s01b + s23b) / 4.0f);
        }
    }
    __syncthreads();

    // ---- basis -> SGPRs (wave-uniform scalars)
    float As[64];
#pragma unroll
    for (int i = 0; i < 64; ++i)
        As[i] = __int_as_float(__builtin_amdgcn_readfirstlane(__float_as_int(Ab[i])));

    const bool isY = (wid < 4);
    float* scr = &Scr[wid][0];

    // ---- load X columns into registers (lane j = column j of its block)
    float X[8];
    if (isY) {
        int blk = wid * 8 + g;         // 0..31 over 2x16 Y-block grid
        int by = blk >> 4, bx = blk & 15;
#pragma unroll
        for (int x = 0; x < 8; ++x) X[x] = Yp[by * 8 + x][bx * 8 + j];
    } else {
        const float (*Cp)[CS] = (wid == 4) ? Cbp : Crp;
#pragma unroll
        for (int x = 0; x < 8; ++x) X[x] = Cp[x][g * 8 + j] - 128.f;
    }

    // ---- pass1 (contract x): T1[y=j][u], ascending-x fmaf chain from 0
    float T[8];
#pragma unroll
    for (int u = 0; u < 8; ++u) {
        float a = 0.f;
#pragma unroll
        for (int x = 0; x < 8; ++x) a = fmaf(X[x], As[x * 8 + u], a);
        T[u] = a;
    }
    // transpose: scatter T1[j][u] -> scr slot (u, j); read row u=j back
#pragma unroll
    for (int u = 0; u < 8; ++u) scr[g * SG + u * 8 + j] = T[u];
    float Tt[8];
    {
        float4 a = *(const float4*)&scr[g * SG + j * 8];
        float4 c = *(const float4*)&scr[g * SG + j * 8 + 4];
        Tt[0] = a.x; Tt[1] = a.y; Tt[2] = a.z; Tt[3] = a.w;
        Tt[4] = c.x; Tt[5] = c.y; Tt[6] = c.z; Tt[7] = c.w;
    }

    // ---- pass2 (contract y): raw[u=j][v], ascending-y fmaf chain from 0
    float R[8];
#pragma unroll
    for (int v = 0; v < 8; ++v) {
        float a = 0.f;
#pragma unroll
        for (int y = 0; y < 8; ++y) a = fmaf(Tt[y], As[y * 8 + v], a);
        R[v] = a;
    }

    // ---- quantize row u=j (bit-critical through rintf), dequant, *alpha2
    float qt[8];
    {
        const float* QT = isY ? QY : QC;
        float4 a = *(const float4*)&QT[j * 8];
        float4 c = *(const float4*)&QT[j * 8 + 4];
        qt[0] = a.x; qt[1] = a.y; qt[2] = a.z; qt[3] = a.w;
        qt[4] = c.x; qt[5] = c.y; qt[6] = c.z; qt[7] = c.w;
    }
    const float RC = 0.70710678118654752440f;
    float au = (j == 0) ? RC : 1.0f;
    float G[8];
#pragma unroll
    for (int v = 0; v < 8; ++v) {
        float av    = (v == 0) ? RC : 1.0f;   // compile-time per v
        float a2    = au * av;                // ALPHA2 fp32 product
        float scale = a2 * 0.25f;             // _SCALE
        float dct   = scale * R[v];
        float xq    = dct / qt[v];            // IEEE fp32 divide (bit-critical)
        float rd    = rintf(xq);              // half-to-even
        float d     = xq - rd;
        float cube  = (d * d) * d;
        float qq    = rd + cube;
        float deq   = qq * qt[v];
        G[v] = deq * a2;
    }
    // transpose G (row u=j -> col v=j)
#pragma unroll
    for (int v = 0; v < 8; ++v) scr[g * SG + v * 8 + j] = G[v];
    float Gt[8];
    {
        float4 a = *(const float4*)&scr[g * SG + j * 8];
        float4 c = *(const float4*)&scr[g * SG + j * 8 + 4];
        Gt[0] = a.x; Gt[1] = a.y; Gt[2] = a.z; Gt[3] = a.w;
        Gt[4] = c.x; Gt[5] = c.y; Gt[6] = c.z; Gt[7] = c.w;
    }

    // ---- IDCT pass1 (contract u): T2[x][v=j]
    float T2[8];
#pragma unroll
    for (int x = 0; x < 8; ++x) {
        float a = 0.f;
#pragma unroll
        for (int u = 0; u < 8; ++u) a = fmaf(Gt[u], As[u * 8 + x], a);
        T2[x] = a;
    }
    // transpose T2 (col v=j -> row x=j)
#pragma unroll
    for (int x = 0; x < 8; ++x) scr[g * SG + x * 8 + j] = T2[x];
    float T2t[8];
    {
        float4 a = *(const float4*)&scr[g * SG + j * 8];
        float4 c = *(const float4*)&scr[g * SG + j * 8 + 4];
        T2t[0] = a.x; T2t[1] = a.y; T2t[2] = a.z; T2t[3] = a.w;
        T2t[4] = c.x; T2t[5] = c.y; T2t[6] = c.z; T2t[7] = c.w;
    }

    // ---- IDCT pass2 (contract v): out[x=j][y] = 0.25*sum + 128
    float O[8];
#pragma unroll
    for (int y = 0; y < 8; ++y) {
        float a = 0.f;
#pragma unroll
        for (int v = 0; v < 8; ++v) a = fmaf(T2t[v], As[v * 8 + y], a);
        O[y] = 0.25f * a + 128.f;
    }

    // ---- write back (in place; block regions disjoint per wave)
    if (isY) {
        int blk = wid * 8 + g;
        int by = blk >> 4, bx = blk & 15;
        *(float4*)&Yp[by * 8 + j][bx * 8]     = make_float4(O[0], O[1], O[2], O[3]);
        *(float4*)&Yp[by * 8 + j][bx * 8 + 4] = make_float4(O[4], O[5], O[6], O[7]);
    } else {
        float (*Cp)[CS] = (wid == 4) ? Cbp : Crp;
        *(float4*)&Cp[j][g * 8]     = make_float4(O[0], O[1], O[2], O[3]);
        *(float4*)&Cp[j][g * 8 + 4] = make_float4(O[4], O[5], O[6], O[7]);
    }
    __syncthreads();

    // ---- output: 256 threads x (2x4) items; upsample chroma, YCbCr->RGB
    // (no fma), clip, *INV255 (post-round: mul ok), nontemporal float4 stores
    if (tid < 256) {
        const float INV255 = 1.0f / 255.0f;
        int rowp = tid >> 5;
        int pc   = (tid & 31) * 4;
        int pr   = rowp * 2;
        int qc   = (tid & 31) * 2;
        float4 ya = *(const float4*)&Yp[pr][pc];
        float4 yb = *(const float4*)&Yp[pr + 1][pc];
        float cb0 = Cbp[rowp][qc]     - 128.f;   // +SHIFT2 separate add
        float cb1 = Cbp[rowp][qc + 1] - 128.f;
        float cr0 = Crp[rowp][qc]     - 128.f;
        float cr1 = Crp[rowp][qc + 1] - 128.f;
        float yy[8] = {ya.x, ya.y, ya.z, ya.w, yb.x, yb.y, yb.z, yb.w};
        float ov[3][8];
#pragma unroll
        for (int k = 0; k < 8; ++k) {
            float cbm = ((k & 3) < 2) ? cb0 : cb1;
            float crm = ((k & 3) < 2) ? cr0 : cr1;
            float rv = yy[k] + (crm * 1.402f);
            float gv = (yy[k] + (cbm * -0.344136f)) + (crm * -0.714136f);
            float bv = yy[k] + (cbm * 1.772f);
            ov[0][k] = fminf(fmaxf(rv, 0.f), 255.f) * INV255;
            ov[1][k] = fminf(fmaxf(gv, 0.f), 255.f) * INV255;
            ov[2][k] = fminf(fmaxf(bv, 0.f), 255.f) * INV255;
        }
        size_t base = ((size_t)b * 3 * HH + (size_t)(h0 + pr)) * WW + (w0 + pc);
#pragma unroll
        for (int ch = 0; ch < 3; ++ch) {
            f4 v0 = {ov[ch][0], ov[ch][1], ov[ch][2], ov[ch][3]};
            f4 v1 = {ov[ch][4], ov[ch][5], ov[ch][6], ov[ch][7]};
            __builtin_nontemporal_store(v0, (f4*)(out + base + ch * plane));
            __builtin_nontemporal_store(v1, (f4*)(out + base + ch * plane + WW));
        }
    }
}

extern "C" void kernel_launch(void* const* d_in, const int* in_sizes, int n_in,
                              void* d_out, int out_size, void* d_ws, size_t ws_size,
                              hipStream_t stream)
{
    const float* x = (const float*)d_in[0];
    float* o = (float*)d_out;
    int batch  = in_sizes[0] / (3 * HH * WW);        // 32
    int blocks = batch * (HH / 16) * (WW / 128);     // 32*32*4 = 4096
    jpeg_fused<<<blocks, 384, 0, stream>>>(x, o);
}

// Round 13
// 41.234 us; speedup vs baseline: 1.7526x; 1.0140x over previous
//
#include <hip/hip_runtime.h>
#include <math.h>

#define HH 512
#define WW 512
#define YS 132   // Y plane row stride (words); 132%32=4 -> spread banks
#define CS 68    // chroma plane row stride
#define SG 68    // scratch group stride (words); 68%32=4

typedef float f2 __attribute__((ext_vector_type(2)));
typedef float f4 __attribute__((ext_vector_type(4)));

static __device__ __forceinline__ f4 vclamp01x255(f4 v) {
    f4 z = 0.f, one = 1.f;
    return __builtin_elementwise_max(__builtin_elementwise_min(v, one), z) * 255.f;
}

__device__ __constant__ float YTAB[64] = {
    16,11,10,16,24,40,51,61,
    12,12,14,19,26,58,60,55,
    14,13,16,24,40,57,69,56,
    14,17,22,29,51,87,80,62,
    18,22,37,56,68,109,103,77,
    24,35,55,64,81,104,113,92,
    49,64,78,87,103,121,120,101,
    72,92,95,98,112,100,103,99};
__device__ __constant__ float CTAB[64] = {
    17,18,24,47,99,99,99,99,
    18,21,26,66,99,99,99,99,
    24,26,56,99,99,99,99,99,
    47,66,99,99,99,99,99,99,
    99,99,99,99,99,99,99,99,
    99,99,99,99,99,99,99,99,
    99,99,99,99,99,99,99,99,
    99,99,99,99,99,99,99,99};

// One workgroup = 128x16 pixel region = 32 Y + 8 Cb + 8 Cr blocks = 48 block
// groups = 6 waves x 8 groups. Lane j of a group holds column j of its 8x8
// block in registers; all 4 matrix passes are PACKED (v_pk_fma_f32) fmaf
// chains over output pairs (2m,2m+1) with basis pairs wave-uniform (SGPR);
// 3 small LDS transposes. Color phases use ext-vector (packed) elementwise
// ops — bit-exact per element. Bit-critical pre-round math identical to
// verified R8/R10/R11/R12:
//  - color: left-assoc mul/add, NO fma; chroma mean paired (s01+s23)/4
//  - DCT: two ascending-k fmaf chains (BLAS sgemm semantics), fp32 T1
//  - quantize: IEEE fp32 scalar div by qt, rintf (half-even), cube in fp32
// Post-round path relaxed (*INV255, nontemporal stores).
__global__ __launch_bounds__(384) void jpeg_fused(const float* __restrict__ in,
                                                  float* __restrict__ out)
{
#pragma clang fp contract(off)
    __shared__ float Yp[16][YS];       // y-128 staged; y2 written back in place
    __shared__ float Cbp[8][CS];       // downsampled cb (+128); cb2 in place
    __shared__ float Crp[8][CS];       // downsampled cr (+128); cr2 in place
    __shared__ float Ab[64];           // basis A[x][u] (np-exact)
    __shared__ float QY[64], QC[64];   // quant tables
    __shared__ float Scr[6][8 * SG];   // per-wave transpose scratch

    const int tid  = threadIdx.x;
    const int wid  = tid >> 6;
    const int lane = tid & 63;
    const int g    = lane >> 3;        // block-group within wave
    const int j    = lane & 7;         // role index within block

    const int bid   = blockIdx.x;
    const int b     = bid >> 7;        // 128 WGs per image (32 strips x 4 cols)
    const int strip = (bid >> 2) & 31;
    const int rcol  = bid & 3;
    const int h0    = strip * 16;
    const int w0    = rcol * 128;
    const size_t plane = (size_t)HH * WW;

    // ---- init: basis (np-exact: int mult, fp64 pi-mult/div, fp64 cos, fp32
    // cast) + quant tables into LDS
    if (tid < 64) {
        int x = tid >> 3, u = tid & 7;
        double arg = (double)((2 * x + 1) * u) * 3.14159265358979323846 / 16.0;
        Ab[tid] = (float)cos(arg);
        QY[tid] = YTAB[tid];
        QC[tid] = CTAB[tid];
    }

    // ---- staging: 256 threads x (2 rows x 4 cols), f4 loads; packed color
    if (tid < 256) {
        int rowp = tid >> 5;           // 0..7 (row pair)
        int pc   = (tid & 31) * 4;     // 0..124
        int pr   = rowp * 2;
        size_t base = ((size_t)b * 3 * HH + (size_t)(h0 + pr)) * WW + (w0 + pc);
        f4 r0 = *(const f4*)(in + base);
        f4 r1 = *(const f4*)(in + base + WW);
        f4 g0 = *(const f4*)(in + base + plane);
        f4 g1 = *(const f4*)(in + base + plane + WW);
        f4 b0 = *(const f4*)(in + base + 2 * plane);
        f4 b1 = *(const f4*)(in + base + 2 * plane + WW);
        r0 = vclamp01x255(r0); r1 = vclamp01x255(r1);
        g0 = vclamp01x255(g0); g1 = vclamp01x255(g1);
        b0 = vclamp01x255(b0); b1 = vclamp01x255(b1);
        // noblas matmul: left-assoc, separate rn mul/add (no fma), elementwise
        f4 y0  = ((r0 * 0.299f)     + (g0 * 0.587f))     + (b0 * 0.114f);
        f4 y1  = ((r1 * 0.299f)     + (g1 * 0.587f))     + (b1 * 0.114f);
        f4 cb0 = ((r0 * -0.168736f) + (g0 * -0.331264f)) + (b0 * 0.5f);
        f4 cb1 = ((r1 * -0.168736f) + (g1 * -0.331264f)) + (b1 * 0.5f);
        f4 cr0 = ((r0 * 0.5f)       + (g0 * -0.418688f)) + (b0 * -0.081312f);
        f4 cr1 = ((r1 * 0.5f)       + (g1 * -0.418688f)) + (b1 * -0.081312f);
        cb0 = cb0 + 128.f; cb1 = cb1 + 128.f;   // +SHIFT1 separate rn add
        cr0 = cr0 + 128.f; cr1 = cr1 + 128.f;
        y0 = y0 - 128.f;  y1 = y1 - 128.f;      // channel does blocks-128
        *(f4*)&Yp[pr][pc]     = y0;
        *(f4*)&Yp[pr + 1][pc] = y1;
        // np multi-axis mean: paired (p00+p01)+(p10+p11), true-div by 4
        int qc = (tid & 31) * 2;
        {
            float s01a = cb0.x + cb0.y, s23a = cb1.x + cb1.y;
            float s01b = cb0.z + cb0.w, s23b = cb1.z + cb1.w;
            *(float2*)&Cbp[rowp][qc] =
                make_float2((s01a + s23a) / 4.0f, (s01b + s23b) / 4.0f);
        }
        {
            float s01a = cr0.x + cr0.y, s23a = cr1.x + cr1.y;
            float s01b = cr0.z + cr0.w, s23b = cr1.z + cr1.w;
            *(float2*)&Crp[rowp][qc] =
                make_float2((s01a + s23a) / 4.0f, (s01b + s23b) / 4.0f);
        }
    }
    __syncthreads();

    // ---- basis pairs -> wave-uniform f2 (SGPR pairs via readfirstlane)
    f2 As2[32];
#pragma unroll
    for (int k = 0; k < 32; ++k) {
        As2[k][0] = __int_as_float(__builtin_amdgcn_readfirstlane(__float_as_int(Ab[2 * k])));
        As2[k][1] = __int_as_float(__builtin_amdgcn_readfirstlane(__float_as_int(Ab[2 * k + 1])));
    }

    const bool isY = (wid < 4);
    float* scr = &Scr[wid][0];

    // ---- load X columns into registers (lane j = column j of its block)
    float X[8];
    if (isY) {
        int blk = wid * 8 + g;         // 0..31 over 2x16 Y-block grid
        int by = blk >> 4, bx = blk & 15;
#pragma unroll
        for (int x = 0; x < 8; ++x) X[x] = Yp[by * 8 + x][bx * 8 + j];
    } else {
        const float (*Cp)[CS] = (wid == 4) ? Cbp : Crp;
#pragma unroll
        for (int x = 0; x < 8; ++x) X[x] = Cp[x][g * 8 + j] - 128.f;
    }

    // ---- pass1 (contract x): T1[y=j][u], ascending-x fmaf chains, packed
    // over output pairs u=(2m,2m+1); per-element bits identical to scalar.
    f2 Tv[4];
#pragma unroll
    for (int m = 0; m < 4; ++m) {
        f2 a = {0.f, 0.f};
#pragma unroll
        for (int x = 0; x < 8; ++x) {
            f2 xx = {X[x], X[x]};
            a = __builtin_elementwise_fma(xx, As2[x * 4 + m], a);
        }
        Tv[m] = a;
    }
    // transpose: scatter T1[j][u] -> scr slot (u, j); read row u=j back
#pragma unroll
    for (int m = 0; m < 4; ++m) {
        scr[g * SG + (2 * m) * 8 + j]     = Tv[m][0];
        scr[g * SG + (2 * m + 1) * 8 + j] = Tv[m][1];
    }
    float Tt[8];
    {
        float4 a = *(const float4*)&scr[g * SG + j * 8];
        float4 c = *(const float4*)&scr[g * SG + j * 8 + 4];
        Tt[0] = a.x; Tt[1] = a.y; Tt[2] = a.z; Tt[3] = a.w;
        Tt[4] = c.x; Tt[5] = c.y; Tt[6] = c.z; Tt[7] = c.w;
    }

    // ---- pass2 (contract y): raw[u=j][v], ascending-y packed chains
    float R[8];
#pragma unroll
    for (int m = 0; m < 4; ++m) {
        f2 a = {0.f, 0.f};
#pragma unroll
        for (int y = 0; y < 8; ++y) {
            f2 tt = {Tt[y], Tt[y]};
            a = __builtin_elementwise_fma(tt, As2[y * 4 + m], a);
        }
        R[2 * m] = a[0]; R[2 * m + 1] = a[1];
    }

    // ---- quantize row u=j (bit-critical, scalar div/rintf), dequant, *alpha2
    float qt[8];
    {
        const float* QT = isY ? QY : QC;
        float4 a = *(const float4*)&QT[j * 8];
        float4 c = *(const float4*)&QT[j * 8 + 4];
        qt[0] = a.x; qt[1] = a.y; qt[2] = a.z; qt[3] = a.w;
        qt[4] = c.x; qt[5] = c.y; qt[6] = c.z; qt[7] = c.w;
    }
    const float RC = 0.70710678118654752440f;
    float au = (j == 0) ? RC : 1.0f;
    float G[8];
#pragma unroll
    for (int v = 0; v < 8; ++v) {
        float av    = (v == 0) ? RC : 1.0f;   // compile-time per v
        float a2    = au * av;                // ALPHA2 fp32 product
        float scale = a2 * 0.25f;             // _SCALE
        float dct   = scale * R[v];
        float xq    = dct / qt[v];            // IEEE fp32 divide (bit-critical)
        float rd    = rintf(xq);              // half-to-even
        float d     = xq - rd;
        float cube  = (d * d) * d;
        float qq    = rd + cube;
        float deq   = qq * qt[v];
        G[v] = deq * a2;
    }
    // transpose G (row u=j -> col v=j)
#pragma unroll
    for (int v = 0; v < 8; ++v) scr[g * SG + v * 8 + j] = G[v];
    float Gt[8];
    {
        float4 a = *(const float4*)&scr[g * SG + j * 8];
        float4 c = *(const float4*)&scr[g * SG + j * 8 + 4];
        Gt[0] = a.x; Gt[1] = a.y; Gt[2] = a.z; Gt[3] = a.w;
        Gt[4] = c.x; Gt[5] = c.y; Gt[6] = c.z; Gt[7] = c.w;
    }

    // ---- IDCT pass1 (contract u): T2[x][v=j], packed over x pairs
    f2 T2v[4];
#pragma unroll
    for (int m = 0; m < 4; ++m) {
        f2 a = {0.f, 0.f};
#pragma unroll
        for (int u = 0; u < 8; ++u) {
            f2 gg = {Gt[u], Gt[u]};
            a = __builtin_elementwise_fma(gg, As2[u * 4 + m], a);
        }
        T2v[m] = a;
    }
    // transpose T2 (col v=j -> row x=j)
#pragma unroll
    for (int m = 0; m < 4; ++m) {
        scr[g * SG + (2 * m) * 8 + j]     = T2v[m][0];
        scr[g * SG + (2 * m + 1) * 8 + j] = T2v[m][1];
    }
    float T2t[8];
    {
        float4 a = *(const float4*)&scr[g * SG + j * 8];
        float4 c = *(const float4*)&scr[g * SG + j * 8 + 4];
        T2t[0] = a.x; T2t[1] = a.y; T2t[2] = a.z; T2t[3] = a.w;
        T2t[4] = c.x; T2t[5] = c.y; T2t[6] = c.z; T2t[7] = c.w;
    }

    // ---- IDCT pass2 (contract v): out[x=j][y] = 0.25*sum + 128, packed
    float O[8];
#pragma unroll
    for (int m = 0; m < 4; ++m) {
        f2 a = {0.f, 0.f};
#pragma unroll
        for (int v = 0; v < 8; ++v) {
            f2 tt = {T2t[v], T2t[v]};
            a = __builtin_elementwise_fma(tt, As2[v * 4 + m], a);
        }
        a = (a * 0.25f) + 128.f;
        O[2 * m] = a[0]; O[2 * m + 1] = a[1];
    }

    // ---- write back (in place; block regions disjoint per wave)
    if (isY) {
        int blk = wid * 8 + g;
        int by = blk >> 4, bx = blk & 15;
        *(float4*)&Yp[by * 8 + j][bx * 8]     = make_float4(O[0], O[1], O[2], O[3]);
        *(float4*)&Yp[by * 8 + j][bx * 8 + 4] = make_float4(O[4], O[5], O[6], O[7]);
    } else {
        float (*Cp)[CS] = (wid == 4) ? Cbp : Crp;
        *(float4*)&Cp[j][g * 8]     = make_float4(O[0], O[1], O[2], O[3]);
        *(float4*)&Cp[j][g * 8 + 4] = make_float4(O[4], O[5], O[6], O[7]);
    }
    __syncthreads();

    // ---- output: 256 threads x (2x4); packed upsample+color, *INV255,
    // nontemporal f4 stores
    if (tid < 256) {
        const float INV255 = 1.0f / 255.0f;
        int rowp = tid >> 5;
        int pc   = (tid & 31) * 4;
        int pr   = rowp * 2;
        int qc   = (tid & 31) * 2;
        f4 ya = *(const f4*)&Yp[pr][pc];
        f4 yb = *(const f4*)&Yp[pr + 1][pc];
        float cb0 = Cbp[rowp][qc]     - 128.f;   // +SHIFT2 separate add
        float cb1 = Cbp[rowp][qc + 1] - 128.f;
        float cr0 = Crp[rowp][qc]     - 128.f;
        float cr1 = Crp[rowp][qc + 1] - 128.f;
        f4 cbm = {cb0, cb0, cb1, cb1};
        f4 crm = {cr0, cr0, cr1, cr1};
        f4 z = 0.f, m255 = 255.f;
#pragma unroll
        for (int row = 0; row < 2; ++row) {
            f4 yy = row ? yb : ya;
            f4 rv = yy + (crm * 1.402f);
            f4 gv = (yy + (cbm * -0.344136f)) + (crm * -0.714136f);
            f4 bv = yy + (cbm * 1.772f);
            rv = __builtin_elementwise_max(__builtin_elementwise_min(rv, m255), z) * INV255;
            gv = __builtin_elementwise_max(__builtin_elementwise_min(gv, m255), z) * INV255;
            bv = __builtin_elementwise_max(__builtin_elementwise_min(bv, m255), z) * INV255;
            size_t base = ((size_t)b * 3 * HH + (size_t)(h0 + pr + row)) * WW + (w0 + pc);
            __builtin_nontemporal_store(rv, (f4*)(out + base));
            __builtin_nontemporal_store(gv, (f4*)(out + base + plane));
            __builtin_nontemporal_store(bv, (f4*)(out + base + 2 * plane));
        }
    }
}

extern "C" void kernel_launch(void* const* d_in, const int* in_sizes, int n_in,
                              void* d_out, int out_size, void* d_ws, size_t ws_size,
                              hipStream_t stream)
{
    const float* x = (const float*)d_in[0];
    float* o = (float*)d_out;
    int batch  = in_sizes[0] / (3 * HH * WW);        // 32
    int blocks = batch * (HH / 16) * (WW / 128);     // 32*32*4 = 4096
    jpeg_fused<<<blocks, 384, 0, stream>>>(x, o);
}